// Round 1
// baseline (269.269 us; speedup 1.0000x reference)
//
#include <hip/hip_runtime.h>

// DIST loss: out = sum_i sqrt((px_i-tx_i)^2 + (py_i-ty_i)^2) / (N+1)
// N = 16,777,216 points, inputs float32 [N,2] each. Memory-bound streaming
// reduction: 268 MB read -> ~43 us floor at 6.3 TB/s.

#define NBLOCKS 1024
#define NTHREADS 256

__global__ __launch_bounds__(NTHREADS)
void dist_partial_kernel(const float4* __restrict__ preds,
                         const float4* __restrict__ targets,
                         float* __restrict__ partials,
                         int n4) {
    int tid = blockIdx.x * NTHREADS + threadIdx.x;
    int stride = gridDim.x * NTHREADS;

    float acc = 0.0f;
    // Each float4 holds two consecutive 2D points: (x0,y0,x1,y1).
    for (int i = tid; i < n4; i += stride) {
        float4 p = preds[i];
        float4 t = targets[i];
        float dx0 = p.x - t.x;
        float dy0 = p.y - t.y;
        float dx1 = p.z - t.z;
        float dy1 = p.w - t.w;
        acc += sqrtf(dx0 * dx0 + dy0 * dy0);
        acc += sqrtf(dx1 * dx1 + dy1 * dy1);
    }

    // wave-64 tree reduce
    #pragma unroll
    for (int off = 32; off > 0; off >>= 1)
        acc += __shfl_down(acc, off, 64);

    __shared__ float wave_sums[NTHREADS / 64];
    int lane = threadIdx.x & 63;
    int wave = threadIdx.x >> 6;
    if (lane == 0) wave_sums[wave] = acc;
    __syncthreads();

    if (threadIdx.x == 0) {
        float s = 0.0f;
        #pragma unroll
        for (int w = 0; w < NTHREADS / 64; ++w) s += wave_sums[w];
        partials[blockIdx.x] = s;
    }
}

__global__ __launch_bounds__(1024)
void dist_final_kernel(const float* __restrict__ partials,
                       float* __restrict__ out,
                       int nblocks, float inv_np1) {
    int tid = threadIdx.x;
    float acc = (tid < nblocks) ? partials[tid] : 0.0f;

    #pragma unroll
    for (int off = 32; off > 0; off >>= 1)
        acc += __shfl_down(acc, off, 64);

    __shared__ float wave_sums[16];
    int lane = tid & 63;
    int wave = tid >> 6;
    if (lane == 0) wave_sums[wave] = acc;
    __syncthreads();

    if (tid == 0) {
        float s = 0.0f;
        #pragma unroll
        for (int w = 0; w < 16; ++w) s += wave_sums[w];
        out[0] = s * inv_np1;
    }
}

extern "C" void kernel_launch(void* const* d_in, const int* in_sizes, int n_in,
                              void* d_out, int out_size, void* d_ws, size_t ws_size,
                              hipStream_t stream) {
    const float4* preds   = (const float4*)d_in[0];
    const float4* targets = (const float4*)d_in[1];
    float* partials = (float*)d_ws;
    float* out = (float*)d_out;

    int n_elems  = in_sizes[0];      // N*2 floats = 33,554,432
    int n_points = n_elems / 2;      // 16,777,216
    int n4       = n_elems / 4;      // float4 count (divisible for this shape)

    // Reference divides by float32(n+1); (float)(n_points+1) rounds to 2^24
    // identically to jnp.asarray(n+1, float32).
    float inv_np1 = 1.0f / (float)(n_points + 1);

    dist_partial_kernel<<<NBLOCKS, NTHREADS, 0, stream>>>(preds, targets, partials, n4);
    dist_final_kernel<<<1, 1024, 0, stream>>>(partials, out, NBLOCKS, inv_np1);
}